// Round 1
// baseline (3885.197 us; speedup 1.0000x reference)
//
#include <hip/hip_runtime.h>
#include <math.h>

// SimpleRetention: B=4, S=2048, H=2048
//   Q = xpos(X@W_Q), K = xpos(X@W_K, down), V = X@W_V
//   att = (Q K^T) * gamma^(n-m) [n>=m], out = att @ V
//
// Round 0: correctness-first fp32 vector GEMMs (no fp32 MFMA on CDNA4).
// All dims are multiples of 128 -> no bounds checks.

#define BM 128
#define BN 128
#define BK 16

static constexpr float LOG_GAMMA_F = -0.031748698314580304f; // ln(0.96875)

__device__ __forceinline__ void xpos_pair(float n, float c0, int mode,
                                          float& cs, float& ss) {
    // c0 = even global column index; pair (c0, c0+1). mode 1 = Q, 2 = K (1/scale)
    const float d = 2048.0f;
    float sv = (c0 + 0.4f * d) / (1.4f * d);
    float power = n * (1.0f / 512.0f);
    if (mode == 2) power = -power;
    float scale = powf(sv, power);
    float inv_freq = powf(10000.0f, -(c0 * 0.5f) * (1.0f / 1024.0f));
    float theta = n * inv_freq;
    float s, c;
    sincosf(theta, &s, &c);
    cs = c * scale;
    ss = s * scale;
}

// C[M,N] = A[M,K] @ B[K,N]; optional xpos epilogue (mode 1/2), optional
// causal k-limit (k < rowBase+BM). Batched via blockIdx.z with strides.
__global__ __launch_bounds__(256, 2)
void gemm_nn(const float* __restrict__ A, const float* __restrict__ B,
             float* __restrict__ C,
             int M, int N, int Kd,
             int lda, int ldb, int ldc,
             long long sA, long long sB, long long sC,
             int mode, int causal, int seq)
{
    A += (long long)blockIdx.z * sA;
    B += (long long)blockIdx.z * sB;
    C += (long long)blockIdx.z * sC;

    __shared__ float As[BK][BM + 4]; // transposed A tile, padded
    __shared__ float Bs[BK][BN];

    const int tid = threadIdx.x;
    const int tx = tid & 15;
    const int ty = tid >> 4;
    const int rowBase = blockIdx.y * BM;
    const int colBase = blockIdx.x * BN;

    const int arow = tid >> 2;        // 0..63
    const int akq  = (tid & 3) * 4;   // 0,4,8,12
    const int brow = tid >> 4;        // 0..15
    const int bcol = (tid & 15) * 4;  // 0..60

    float acc[8][8];
#pragma unroll
    for (int i = 0; i < 8; ++i)
#pragma unroll
        for (int j = 0; j < 8; ++j) acc[i][j] = 0.0f;

    int kmax = Kd;
    if (causal) { int km = rowBase + BM; kmax = km < Kd ? km : Kd; }

    const float* Aptr0 = A + (size_t)(rowBase + arow) * lda + akq;
    const float* Aptr1 = Aptr0 + (size_t)64 * lda;
    const float* Bptr  = B + (size_t)brow * ldb + colBase + bcol;

    for (int k0 = 0; k0 < kmax; k0 += BK) {
        float4 a0 = *(const float4*)(Aptr0 + k0);
        float4 a1 = *(const float4*)(Aptr1 + k0);
        const float* bp = Bptr + (size_t)k0 * ldb;
        float4 b0 = *(const float4*)(bp);
        float4 b1 = *(const float4*)(bp + 64);
        __syncthreads(); // protect previous iter's LDS reads
        As[akq + 0][arow] = a0.x; As[akq + 1][arow] = a0.y;
        As[akq + 2][arow] = a0.z; As[akq + 3][arow] = a0.w;
        As[akq + 0][arow + 64] = a1.x; As[akq + 1][arow + 64] = a1.y;
        As[akq + 2][arow + 64] = a1.z; As[akq + 3][arow + 64] = a1.w;
        *(float4*)&Bs[brow][bcol] = b0;
        *(float4*)&Bs[brow][bcol + 64] = b1;
        __syncthreads();
#pragma unroll
        for (int kk = 0; kk < BK; ++kk) {
            float ar[8], br[8];
            *(float4*)&ar[0] = *(const float4*)&As[kk][ty * 4];
            *(float4*)&ar[4] = *(const float4*)&As[kk][64 + ty * 4];
            *(float4*)&br[0] = *(const float4*)&Bs[kk][tx * 4];
            *(float4*)&br[4] = *(const float4*)&Bs[kk][64 + tx * 4];
#pragma unroll
            for (int i = 0; i < 8; ++i)
#pragma unroll
                for (int j = 0; j < 8; ++j)
                    acc[i][j] = fmaf(ar[i], br[j], acc[i][j]);
        }
    }

#pragma unroll
    for (int i = 0; i < 8; ++i) {
        int grow = rowBase + ((i < 4) ? (ty * 4 + i) : (64 + ty * 4 + (i - 4)));
        if (mode != 0) {
            float n = (float)(grow % seq);
#pragma unroll
            for (int g = 0; g < 2; ++g) {
                int cst = colBase + g * 64 + tx * 4;
#pragma unroll
                for (int jp = 0; jp < 4; jp += 2) {
                    float cs, ss;
                    xpos_pair(n, (float)(cst + jp), mode, cs, ss);
                    float x1 = acc[i][g * 4 + jp];
                    float x2 = acc[i][g * 4 + jp + 1];
                    acc[i][g * 4 + jp]     = x1 * cs - x2 * ss;
                    acc[i][g * 4 + jp + 1] = x2 * cs + x1 * ss;
                }
            }
        }
        float4 o0 = make_float4(acc[i][0], acc[i][1], acc[i][2], acc[i][3]);
        float4 o1 = make_float4(acc[i][4], acc[i][5], acc[i][6], acc[i][7]);
        *(float4*)&C[(size_t)grow * ldc + colBase + tx * 4] = o0;
        *(float4*)&C[(size_t)grow * ldc + colBase + 64 + tx * 4] = o1;
    }
}

// att[n,m] = (sum_h Q[n,h]*K[m,h]) * gamma^(n-m) for n>=m else 0.
// Strictly-upper 128x128 blocks: write zeros, skip compute.
__global__ __launch_bounds__(256, 2)
void gemm_nt_decay(const float* __restrict__ Q, const float* __restrict__ Kp,
                   float* __restrict__ Catt,
                   int Hd, int ldq, int ldk, int ldc,
                   long long sQ, long long sK, long long sC)
{
    Q    += (long long)blockIdx.z * sQ;
    Kp   += (long long)blockIdx.z * sK;
    Catt += (long long)blockIdx.z * sC;

    const int tid = threadIdx.x;
    const int tx = tid & 15;
    const int ty = tid >> 4;
    const int rowBase = blockIdx.y * BM; // n
    const int colBase = blockIdx.x * BN; // m

    if (blockIdx.y < blockIdx.x) { // all n < all m -> zero block
        float4 z = make_float4(0.f, 0.f, 0.f, 0.f);
#pragma unroll
        for (int i = 0; i < 8; ++i) {
            int grow = rowBase + ((i < 4) ? (ty * 4 + i) : (64 + ty * 4 + (i - 4)));
            *(float4*)&Catt[(size_t)grow * ldc + colBase + tx * 4] = z;
            *(float4*)&Catt[(size_t)grow * ldc + colBase + 64 + tx * 4] = z;
        }
        return;
    }

    __shared__ float Qs[BK][BM + 4];
    __shared__ float Ks[BK][BM + 4];

    const int arow = tid >> 2;
    const int akq  = (tid & 3) * 4;

    float acc[8][8];
#pragma unroll
    for (int i = 0; i < 8; ++i)
#pragma unroll
        for (int j = 0; j < 8; ++j) acc[i][j] = 0.0f;

    const float* qp0 = Q  + (size_t)(rowBase + arow) * ldq + akq;
    const float* qp1 = qp0 + (size_t)64 * ldq;
    const float* kp0 = Kp + (size_t)(colBase + arow) * ldk + akq;
    const float* kp1 = kp0 + (size_t)64 * ldk;

    for (int k0 = 0; k0 < Hd; k0 += BK) {
        float4 a0 = *(const float4*)(qp0 + k0);
        float4 a1 = *(const float4*)(qp1 + k0);
        float4 b0 = *(const float4*)(kp0 + k0);
        float4 b1 = *(const float4*)(kp1 + k0);
        __syncthreads();
        Qs[akq + 0][arow] = a0.x; Qs[akq + 1][arow] = a0.y;
        Qs[akq + 2][arow] = a0.z; Qs[akq + 3][arow] = a0.w;
        Qs[akq + 0][arow + 64] = a1.x; Qs[akq + 1][arow + 64] = a1.y;
        Qs[akq + 2][arow + 64] = a1.z; Qs[akq + 3][arow + 64] = a1.w;
        Ks[akq + 0][arow] = b0.x; Ks[akq + 1][arow] = b0.y;
        Ks[akq + 2][arow] = b0.z; Ks[akq + 3][arow] = b0.w;
        Ks[akq + 0][arow + 64] = b1.x; Ks[akq + 1][arow + 64] = b1.y;
        Ks[akq + 2][arow + 64] = b1.z; Ks[akq + 3][arow + 64] = b1.w;
        __syncthreads();
#pragma unroll
        for (int kk = 0; kk < BK; ++kk) {
            float ar[8], br[8];
            *(float4*)&ar[0] = *(const float4*)&Qs[kk][ty * 4];
            *(float4*)&ar[4] = *(const float4*)&Qs[kk][64 + ty * 4];
            *(float4*)&br[0] = *(const float4*)&Ks[kk][tx * 4];
            *(float4*)&br[4] = *(const float4*)&Ks[kk][64 + tx * 4];
#pragma unroll
            for (int i = 0; i < 8; ++i)
#pragma unroll
                for (int j = 0; j < 8; ++j)
                    acc[i][j] = fmaf(ar[i], br[j], acc[i][j]);
        }
    }

#pragma unroll
    for (int i = 0; i < 8; ++i) {
        int n = rowBase + ((i < 4) ? (ty * 4 + i) : (64 + ty * 4 + (i - 4)));
        float vals[8];
#pragma unroll
        for (int j = 0; j < 8; ++j) {
            int m = colBase + ((j < 4) ? (tx * 4 + j) : (64 + tx * 4 + (j - 4)));
            int dnm = n - m;
            vals[j] = (dnm >= 0) ? acc[i][j] * expf((float)dnm * LOG_GAMMA_F)
                                 : 0.0f;
        }
        float4 o0 = make_float4(vals[0], vals[1], vals[2], vals[3]);
        float4 o1 = make_float4(vals[4], vals[5], vals[6], vals[7]);
        *(float4*)&Catt[(size_t)n * ldc + colBase + tx * 4] = o0;
        *(float4*)&Catt[(size_t)n * ldc + colBase + 64 + tx * 4] = o1;
    }
}

extern "C" void kernel_launch(void* const* d_in, const int* in_sizes, int n_in,
                              void* d_out, int out_size, void* d_ws, size_t ws_size,
                              hipStream_t stream) {
    const int B = 4, S = 2048, H = 2048;
    const int M = B * S;

    const float* X  = (const float*)d_in[0];
    const float* WQ = (const float*)d_in[1];
    const float* WK = (const float*)d_in[2];
    const float* WV = (const float*)d_in[3];
    float* out = (float*)d_out;

    // workspace layout: Q | K | V | att  (3*64MB + 64MB = 268.4 MB)
    float* Q   = (float*)d_ws;
    float* Kt  = Q  + (size_t)M * H;
    float* V   = Kt + (size_t)M * H;
    float* att = V  + (size_t)M * H;

    dim3 blk(256);
    dim3 g1(H / BN, M / BM, 1);
    // Q = xpos(X@WQ), K = xpos_down(X@WK), V = X@WV
    gemm_nn<<<g1, blk, 0, stream>>>(X, WQ, Q,  M, H, H, H, H, H, 0, 0, 0, 1, 0, S);
    gemm_nn<<<g1, blk, 0, stream>>>(X, WK, Kt, M, H, H, H, H, H, 0, 0, 0, 2, 0, S);
    gemm_nn<<<g1, blk, 0, stream>>>(X, WV, V,  M, H, H, H, H, H, 0, 0, 0, 0, 0, S);

    dim3 g2(S / BN, S / BM, B);
    // att = (Q K^T) * decay, batched
    gemm_nt_decay<<<g2, blk, 0, stream>>>(Q, Kt, att, H, H, H, S,
                                          (long long)S * H, (long long)S * H,
                                          (long long)S * S);
    // out = att @ V, causal k-limit, batched
    gemm_nn<<<g2, blk, 0, stream>>>(att, V, out, S, H, S, S, H, H,
                                    (long long)S * S, (long long)S * H,
                                    (long long)S * H, 0, 1, S);
}

// Round 3
// 599.492 us; speedup vs baseline: 6.4808x; 6.4808x over previous
//
#include <hip/hip_runtime.h>
#include <math.h>

// SimpleRetention, bf16 MFMA version (m97-style 128x128xBK32 tiles).
// All operands stored row-major over K ("NT"): A rows = out rows, B rows = out cols.
//   stage1: Q/K/V = Xbf @ Wt^T  (Wt pre-transposed bf16), xpos epilogue on Q/K,
//           V written transposed (Vt[h][m]) for stage 3.
//   stage2: att[n][m] = (Q K^T) * gamma^(n-m) [n>=m], bf16.
//   stage3: out^T computed as Vt (rows h) x att (rows n): coalesced fp32 store.
// R2 fix: batch strides were MH/2 (2x too large -> OOB fault); correct is S*H.

typedef __attribute__((ext_vector_type(8))) short short8;
typedef __attribute__((ext_vector_type(4))) float f32x4;
typedef __attribute__((ext_vector_type(4))) unsigned short us4;

#define BM 128
#define BN 128
#define BK 32

static __device__ __forceinline__ unsigned short f2bf(float f) {
    unsigned int u = __float_as_uint(f);
    u += 0x7FFFu + ((u >> 16) & 1u);   // RNE
    return (unsigned short)(u >> 16);
}

static __device__ __forceinline__ void gload16(const unsigned short* g, unsigned short* l) {
    __builtin_amdgcn_global_load_lds(
        (const __attribute__((address_space(1))) unsigned int*)g,
        (__attribute__((address_space(3))) unsigned int*)l, 16, 0, 0);
}

// MODE: 0 = V (store bf16 transposed, ld 8192)
//       1 = Q (xpos, store bf16, ld 2048)
//       2 = K (xpos downscale, store bf16, ld 2048)
//       3 = att (decay+causal, store bf16, ld 2048, zero upper blocks)
//       4 = out (causal k-limit, store fp32 transposed-C, ld 2048)
template <int MODE>
__global__ __launch_bounds__(256)
void gemm_bt(const unsigned short* __restrict__ A,
             const unsigned short* __restrict__ Bt,
             void* __restrict__ Cv,
             int lda, int ldb, int Kd,
             long long sA, long long sB, long long sC)
{
    constexpr int S = 2048, H = 2048;
    const int rowBase = blockIdx.y * BM;
    const int colBase = blockIdx.x * BN;

    if (MODE == 3 && blockIdx.x > blockIdx.y) { // strictly-upper: zeros
        unsigned short* att = (unsigned short*)Cv + (long long)blockIdx.z * sC;
        int r = threadIdx.x >> 1, c = (threadIdx.x & 1) * 64;
        unsigned short* p = att + (size_t)(rowBase + r) * S + colBase + c;
        uint4 z = make_uint4(0, 0, 0, 0);
#pragma unroll
        for (int q = 0; q < 8; ++q) ((uint4*)p)[q] = z;
        return;
    }

    A  += (long long)blockIdx.z * sA;
    Bt += (long long)blockIdx.z * sB;

    __shared__ unsigned short As[BM * BK];
    __shared__ unsigned short Bs[BN * BK];

    const int tid  = threadIdx.x;
    const int wave = tid >> 6;
    const int lane = tid & 63;
    const int wm = (wave & 1) * 64;
    const int wn = (wave >> 1) * 64;

    f32x4 acc[4][4];
#pragma unroll
    for (int i = 0; i < 4; ++i)
#pragma unroll
        for (int j = 0; j < 4; ++j) acc[i][j] = (f32x4){0.f, 0.f, 0.f, 0.f};

    int kmax = Kd;
    if (MODE == 4) { int km = colBase + BN; kmax = km < Kd ? km : Kd; }

    // staging: wave w covers tile rows [w*32, w*32+32), 2 loads of 16 rows each
    const int sr = wave * 32 + (lane >> 2);
    const int sc = (lane & 3) * 8;
    const unsigned short* ga = A  + (size_t)(rowBase + sr) * lda + sc;
    const unsigned short* gb = Bt + (size_t)(colBase + sr) * ldb + sc;
    unsigned short* lA = As + wave * 1024; // wave-uniform LDS dest (lane*16B implicit)
    unsigned short* lB = Bs + wave * 1024;

    gload16(ga, lA); gload16(ga + 16 * (size_t)lda, lA + 512);
    gload16(gb, lB); gload16(gb + 16 * (size_t)ldb, lB + 512);

    const int fr = lane & 15;
    const int fk = (lane >> 4) * 8;

    for (int k0 = 0; k0 < kmax; k0 += BK) {
        __syncthreads(); // drains vmcnt: tile k0 resident in LDS
        short8 af[4], bf[4];
#pragma unroll
        for (int i = 0; i < 4; ++i)
            af[i] = *(const short8*)&As[(wm + i * 16 + fr) * BK + fk];
#pragma unroll
        for (int j = 0; j < 4; ++j)
            bf[j] = *(const short8*)&Bs[(wn + j * 16 + fr) * BK + fk];
        __syncthreads(); // all waves done reading LDS
        if (k0 + BK < kmax) {
            const unsigned short* ga2 = ga + k0 + BK;
            const unsigned short* gb2 = gb + k0 + BK;
            gload16(ga2, lA); gload16(ga2 + 16 * (size_t)lda, lA + 512);
            gload16(gb2, lB); gload16(gb2 + 16 * (size_t)ldb, lB + 512);
        }
#pragma unroll
        for (int i = 0; i < 4; ++i)
#pragma unroll
            for (int j = 0; j < 4; ++j)
                acc[i][j] = __builtin_amdgcn_mfma_f32_16x16x32_bf16(af[i], bf[j], acc[i][j], 0, 0, 0);
    }

    // C/D layout: col = lane&15, row = (lane>>4)*4 + reg
    if (MODE == 1 || MODE == 2) {
        unsigned short* Co = (unsigned short*)Cv;
        const float psgn = (MODE == 2) ? -1.953125e-3f : 1.953125e-3f; // ±1/512
#pragma unroll
        for (int j = 0; j < 4; ++j) {
            int gc = colBase + wn + j * 16 + fr;
            float c0 = (float)(gc & ~1);
            float l2sv = log2f((c0 + 819.2f) * (1.0f / 2867.2f)) * psgn;
            float invf = exp2f(c0 * -0.0064881407f); // 10000^(-c0/2048)
            float s1, c1;
            sincosf(invf, &s1, &c1);
#pragma unroll
            for (int i = 0; i < 4; ++i) {
                int gr0 = rowBase + wm + i * 16 + (lane >> 4) * 4;
                float fn = (float)(gr0 & (S - 1));
                float sN, cN;
                sincosf(fn * invf, &sN, &cN);
#pragma unroll
                for (int r = 0; r < 4; ++r) {
                    float scale = exp2f(fn * l2sv);
                    float cs = cN * scale, ss = sN * scale;
                    float v = acc[i][j][r];
                    float o = __shfl_xor(v, 1);
                    float res = (gc & 1) ? fmaf(v, cs, o * ss) : fmaf(v, cs, -o * ss);
                    Co[(size_t)(gr0 + r) * H + gc] = f2bf(res);
                    float sn2 = sN * c1 + cN * s1; // rotate by invf for next row
                    cN = cN * c1 - sN * s1;
                    sN = sn2;
                    fn += 1.0f;
                }
            }
        }
    } else if (MODE == 0) {
        unsigned short* Vt = (unsigned short*)Cv;
#pragma unroll
        for (int j = 0; j < 4; ++j) {
            int gh = colBase + wn + j * 16 + fr;
#pragma unroll
            for (int i = 0; i < 4; ++i) {
                int gm0 = rowBase + wm + i * 16 + (lane >> 4) * 4;
                us4 p;
#pragma unroll
                for (int r = 0; r < 4; ++r) p[r] = f2bf(acc[i][j][r]);
                *(us4*)&Vt[(size_t)gh * 8192 + gm0] = p;
            }
        }
    } else if (MODE == 3) {
        unsigned short* att = (unsigned short*)Cv + (long long)blockIdx.z * sC;
#pragma unroll
        for (int j = 0; j < 4; ++j) {
            int m = colBase + wn + j * 16 + fr;
#pragma unroll
            for (int i = 0; i < 4; ++i) {
                int n0 = rowBase + wm + i * 16 + (lane >> 4) * 4;
#pragma unroll
                for (int r = 0; r < 4; ++r) {
                    int d = n0 + r - m;
                    float v = (d >= 0) ? acc[i][j][r] * exp2f((float)d * -0.045803598f) : 0.0f;
                    att[(size_t)(n0 + r) * S + m] = f2bf(v);
                }
            }
        }
    } else { // MODE 4: C rows = h, cols = n; store out[n][h] -> float4 per lane
        float* Co = (float*)Cv + (long long)blockIdx.z * sC;
#pragma unroll
        for (int j = 0; j < 4; ++j) {
            int gn = colBase + wn + j * 16 + fr;
#pragma unroll
            for (int i = 0; i < 4; ++i) {
                int gh0 = rowBase + wm + i * 16 + (lane >> 4) * 4;
                *(f32x4*)&Co[(size_t)gn * H + gh0] = acc[i][j];
            }
        }
    }
}

__global__ __launch_bounds__(256)
void cvt_f32_bf16(const float* __restrict__ x, unsigned short* __restrict__ y) {
    int i = blockIdx.x * 256 + threadIdx.x;
    float4 v = ((const float4*)x)[i];
    us4 o = {f2bf(v.x), f2bf(v.y), f2bf(v.z), f2bf(v.w)};
    ((us4*)y)[i] = o;
}

// W [2048][2048] fp32 -> Wt [n][k] bf16
__global__ __launch_bounds__(256)
void cvt_transpose(const float* __restrict__ W, unsigned short* __restrict__ Wt) {
    __shared__ float t[64][65];
    int bx = blockIdx.x * 64, by = blockIdx.y * 64;
    int tx = threadIdx.x & 63, ty = threadIdx.x >> 6;
#pragma unroll
    for (int r = 0; r < 64; r += 4)
        t[ty + r][tx] = W[(size_t)(by + ty + r) * 2048 + bx + tx];
    __syncthreads();
#pragma unroll
    for (int r = 0; r < 64; r += 4)
        Wt[(size_t)(bx + ty + r) * 2048 + by + tx] = f2bf(t[tx][ty + r]);
}

extern "C" void kernel_launch(void* const* d_in, const int* in_sizes, int n_in,
                              void* d_out, int out_size, void* d_ws, size_t ws_size,
                              hipStream_t stream) {
    const int S = 2048, H = 2048;
    const long long MH = 16777216;        // 8192*2048 (elements)
    const long long HH = 4194304;         // 2048*2048
    const long long SH = (long long)S * H; // per-batch stride = 4194304

    const float* X  = (const float*)d_in[0];
    const float* WQ = (const float*)d_in[1];
    const float* WK = (const float*)d_in[2];
    const float* WV = (const float*)d_in[3];
    float* out = (float*)d_out;

    unsigned short* Xb  = (unsigned short*)d_ws;
    unsigned short* WtQ = Xb  + MH;
    unsigned short* WtK = WtQ + HH;
    unsigned short* WtV = WtK + HH;
    unsigned short* Qb  = WtV + HH;
    unsigned short* Kb  = Qb  + MH;
    unsigned short* Vt  = Kb  + MH;
    unsigned short* att = Vt  + MH;

    cvt_f32_bf16<<<16384, 256, 0, stream>>>(X, Xb);
    cvt_transpose<<<dim3(32, 32), 256, 0, stream>>>(WQ, WtQ);
    cvt_transpose<<<dim3(32, 32), 256, 0, stream>>>(WK, WtK);
    cvt_transpose<<<dim3(32, 32), 256, 0, stream>>>(WV, WtV);

    dim3 g1(16, 64, 1);
    gemm_bt<1><<<g1, 256, 0, stream>>>(Xb, WtQ, Qb, H, H, H, 0, 0, 0);
    gemm_bt<2><<<g1, 256, 0, stream>>>(Xb, WtK, Kb, H, H, H, 0, 0, 0);
    gemm_bt<0><<<g1, 256, 0, stream>>>(Xb, WtV, Vt, H, H, H, 0, 0, 0);

    dim3 g2(16, 16, 4);
    // stage 2: att = (Q K^T) * decay; per-batch stride S*H for Q/K, S*S for att
    gemm_bt<3><<<g2, 256, 0, stream>>>(Qb, Kb, att, H, H, H, SH, SH, (long long)S * S);
    // stage 3: out^T = Vt x att; sA=2048 is the batch column-offset into Vt[h][8192]
    gemm_bt<4><<<g2, 256, 0, stream>>>(Vt, att, out, 8192, S, S, S, (long long)S * S, SH);
}

// Round 4
// 487.963 us; speedup vs baseline: 7.9621x; 1.2286x over previous
//
#include <hip/hip_runtime.h>
#include <math.h>

// SimpleRetention bf16 MFMA, round 4:
//  - BK=64 (32 MFMA per barrier pair), 32 KB LDS
//  - XOR-swizzled LDS chunks -> conflict-free ds_read_b128
//  - Q/K/V projections merged into ONE dispatch (B = [WtQ;WtK;WtV], grid 48x64)
// Pipeline: stage1 QKV proj (+xpos on Q/K, V stored transposed),
//           stage2 att = (Q K^T)*decay (bf16), stage3 out^T = Vt x att (fp32).

typedef __attribute__((ext_vector_type(8))) short short8;
typedef __attribute__((ext_vector_type(4))) float f32x4;
typedef __attribute__((ext_vector_type(4))) unsigned short us4;

#define BM 128
#define BN 128
#define BK 64

static __device__ __forceinline__ unsigned short f2bf(float f) {
    unsigned int u = __float_as_uint(f);
    u += 0x7FFFu + ((u >> 16) & 1u);   // RNE
    return (unsigned short)(u >> 16);
}

static __device__ __forceinline__ void gload16(const unsigned short* g, unsigned short* l) {
    __builtin_amdgcn_global_load_lds(
        (const __attribute__((address_space(1))) unsigned int*)g,
        (__attribute__((address_space(3))) unsigned int*)l, 16, 0, 0);
}

// STAGE: 1 = merged QKV projection (xpos on Q/K, V transposed store)
//        3 = att (decay+causal, bf16, zero upper blocks)
//        4 = out (causal k-limit, fp32 transposed-C store)
template <int STAGE>
__global__ __launch_bounds__(256)
void gemm_bt(const unsigned short* __restrict__ A,
             const unsigned short* __restrict__ Bt,
             void* __restrict__ Cv,
             unsigned short* __restrict__ Cq,
             unsigned short* __restrict__ Ck,
             unsigned short* __restrict__ Cvt,
             int lda, int ldb, int Kd,
             long long sA, long long sB, long long sC)
{
    constexpr int S = 2048, H = 2048;
    const int rowBase = blockIdx.y * BM;
    const int colBase = blockIdx.x * BN;

    if (STAGE == 3 && blockIdx.x > blockIdx.y) { // strictly-upper: zeros
        unsigned short* att = (unsigned short*)Cv + (long long)blockIdx.z * sC;
        int r = threadIdx.x >> 1, c = (threadIdx.x & 1) * 64;
        unsigned short* p = att + (size_t)(rowBase + r) * S + colBase + c;
        uint4 z = make_uint4(0, 0, 0, 0);
#pragma unroll
        for (int q = 0; q < 8; ++q) ((uint4*)p)[q] = z;
        return;
    }

    A  += (long long)blockIdx.z * sA;
    Bt += (long long)blockIdx.z * sB;

    __shared__ unsigned short As[BM * BK]; // row-major [128][64], chunks xor-swizzled
    __shared__ unsigned short Bs[BN * BK];

    const int tid  = threadIdx.x;
    const int wave = tid >> 6;
    const int lane = tid & 63;
    const int wm = (wave & 1) * 64;
    const int wn = (wave >> 1) * 64;

    f32x4 acc[4][4];
#pragma unroll
    for (int i = 0; i < 4; ++i)
#pragma unroll
        for (int j = 0; j < 4; ++j) acc[i][j] = (f32x4){0.f, 0.f, 0.f, 0.f};

    int kmax = Kd;
    if (STAGE == 4) { int km = colBase + BN; kmax = km < Kd ? km : Kd; }

    // Staging: wave w covers rows [w*32, w*32+32), 4 gload16 each for A and B.
    // Lane -> (row = lane>>3, dstChunk = lane&7); source chunk xor-swizzled so
    // LDS chunk position p holds source chunk p ^ (row&7).
    const int srow = wave * 32 + (lane >> 3);
    const int schunk = ((lane & 7) ^ ((lane >> 3) & 7)) * 8;
    const unsigned short* ga = A  + (size_t)(rowBase + srow) * lda + schunk;
    const unsigned short* gb = Bt + (size_t)(colBase + srow) * ldb + schunk;
    unsigned short* lA = As + wave * 2048; // + q*512 per 8-row group
    unsigned short* lB = Bs + wave * 2048;

#pragma unroll
    for (int q = 0; q < 4; ++q) {
        gload16(ga + (size_t)q * 8 * lda, lA + q * 512);
        gload16(gb + (size_t)q * 8 * ldb, lB + q * 512);
    }

    const int fr = lane & 15;
    const int qd = lane >> 4;        // quad 0..3, k-base = qd*8
    const int fsw = fr & 7;          // xor key per fragment row

    for (int k0 = 0; k0 < kmax; k0 += BK) {
        __syncthreads(); // tile k0 resident
        short8 af0[4], bf0[4], af1[4], bf1[4];
#pragma unroll
        for (int i = 0; i < 4; ++i) {
            int row = wm + i * 16 + fr;
            af0[i] = *(const short8*)&As[row * 64 + ((qd ^ fsw) * 8)];
            af1[i] = *(const short8*)&As[row * 64 + (((4 + qd) ^ fsw) * 8)];
        }
#pragma unroll
        for (int j = 0; j < 4; ++j) {
            int row = wn + j * 16 + fr;
            bf0[j] = *(const short8*)&Bs[row * 64 + ((qd ^ fsw) * 8)];
            bf1[j] = *(const short8*)&Bs[row * 64 + (((4 + qd) ^ fsw) * 8)];
        }
        __syncthreads(); // all reads drained
        if (k0 + BK < kmax) {
            const unsigned short* ga2 = ga + k0 + BK;
            const unsigned short* gb2 = gb + k0 + BK;
#pragma unroll
            for (int q = 0; q < 4; ++q) {
                gload16(ga2 + (size_t)q * 8 * lda, lA + q * 512);
                gload16(gb2 + (size_t)q * 8 * ldb, lB + q * 512);
            }
        }
#pragma unroll
        for (int i = 0; i < 4; ++i)
#pragma unroll
            for (int j = 0; j < 4; ++j)
                acc[i][j] = __builtin_amdgcn_mfma_f32_16x16x32_bf16(af0[i], bf0[j], acc[i][j], 0, 0, 0);
#pragma unroll
        for (int i = 0; i < 4; ++i)
#pragma unroll
            for (int j = 0; j < 4; ++j)
                acc[i][j] = __builtin_amdgcn_mfma_f32_16x16x32_bf16(af1[i], bf1[j], acc[i][j], 0, 0, 0);
    }

    // C/D layout: col = lane&15, row = (lane>>4)*4 + reg
    if (STAGE == 1) {
        const int mode = colBase >> 11; // 0=Q, 1=K, 2=V
        if (mode < 2) {
            unsigned short* Co = (mode == 0) ? Cq : Ck;
            const float psgn = (mode == 1) ? -1.953125e-3f : 1.953125e-3f; // ±1/512
#pragma unroll
            for (int j = 0; j < 4; ++j) {
                int gc = (colBase & 2047) + wn + j * 16 + fr;
                float c0 = (float)(gc & ~1);
                float l2sv = log2f((c0 + 819.2f) * (1.0f / 2867.2f)) * psgn;
                float invf = exp2f(c0 * -0.0064881407f); // 10000^(-c0/2048)
                float s1, c1;
                sincosf(invf, &s1, &c1);
#pragma unroll
                for (int i = 0; i < 4; ++i) {
                    int gr0 = rowBase + wm + i * 16 + qd * 4;
                    float fn = (float)(gr0 & (S - 1));
                    float sN, cN;
                    sincosf(fn * invf, &sN, &cN);
#pragma unroll
                    for (int r = 0; r < 4; ++r) {
                        float scale = exp2f(fn * l2sv);
                        float cs = cN * scale, ss = sN * scale;
                        float v = acc[i][j][r];
                        float o = __shfl_xor(v, 1);
                        float res = (gc & 1) ? fmaf(v, cs, o * ss) : fmaf(v, cs, -o * ss);
                        Co[(size_t)(gr0 + r) * H + gc] = f2bf(res);
                        float sn2 = sN * c1 + cN * s1; // rotate by invf
                        cN = cN * c1 - sN * s1;
                        sN = sn2;
                        fn += 1.0f;
                    }
                }
            }
        } else { // V: store transposed Vt[h][8192]
#pragma unroll
            for (int j = 0; j < 4; ++j) {
                int gh = (colBase & 2047) + wn + j * 16 + fr;
#pragma unroll
                for (int i = 0; i < 4; ++i) {
                    int gm0 = rowBase + wm + i * 16 + qd * 4;
                    us4 p;
#pragma unroll
                    for (int r = 0; r < 4; ++r) p[r] = f2bf(acc[i][j][r]);
                    *(us4*)&Cvt[(size_t)gh * 8192 + gm0] = p;
                }
            }
        }
    } else if (STAGE == 3) {
        unsigned short* att = (unsigned short*)Cv + (long long)blockIdx.z * sC;
#pragma unroll
        for (int j = 0; j < 4; ++j) {
            int m = colBase + wn + j * 16 + fr;
#pragma unroll
            for (int i = 0; i < 4; ++i) {
                int n0 = rowBase + wm + i * 16 + qd * 4;
#pragma unroll
                for (int r = 0; r < 4; ++r) {
                    int d = n0 + r - m;
                    float v = (d >= 0) ? acc[i][j][r] * exp2f((float)d * -0.045803598f) : 0.0f;
                    att[(size_t)(n0 + r) * S + m] = f2bf(v);
                }
            }
        }
    } else { // STAGE 4: C rows = h, cols = n; store out[n][h] as float4
        float* Co = (float*)Cv + (long long)blockIdx.z * sC;
#pragma unroll
        for (int j = 0; j < 4; ++j) {
            int gn = colBase + wn + j * 16 + fr;
#pragma unroll
            for (int i = 0; i < 4; ++i) {
                int gh0 = rowBase + wm + i * 16 + qd * 4;
                *(f32x4*)&Co[(size_t)gn * H + gh0] = acc[i][j];
            }
        }
    }
}

__global__ __launch_bounds__(256)
void cvt_f32_bf16(const float* __restrict__ x, unsigned short* __restrict__ y) {
    int i = blockIdx.x * 256 + threadIdx.x;
    float4 v = ((const float4*)x)[i];
    us4 o = {f2bf(v.x), f2bf(v.y), f2bf(v.z), f2bf(v.w)};
    ((us4*)y)[i] = o;
}

// three W [2048][2048] fp32 -> WtAll [6144][2048] bf16 (transposed per chunk)
__global__ __launch_bounds__(256)
void cvt_transpose3(const float* __restrict__ W0, const float* __restrict__ W1,
                    const float* __restrict__ W2, unsigned short* __restrict__ Wt) {
    __shared__ float t[64][65];
    const float* W = (blockIdx.z == 0) ? W0 : (blockIdx.z == 1) ? W1 : W2;
    unsigned short* Wo = Wt + (size_t)blockIdx.z * 4194304;
    int bx = blockIdx.x * 64, by = blockIdx.y * 64;
    int tx = threadIdx.x & 63, ty = threadIdx.x >> 6;
#pragma unroll
    for (int r = 0; r < 64; r += 4)
        t[ty + r][tx] = W[(size_t)(by + ty + r) * 2048 + bx + tx];
    __syncthreads();
#pragma unroll
    for (int r = 0; r < 64; r += 4)
        Wo[(size_t)(bx + ty + r) * 2048 + by + tx] = f2bf(t[tx][ty + r]);
}

extern "C" void kernel_launch(void* const* d_in, const int* in_sizes, int n_in,
                              void* d_out, int out_size, void* d_ws, size_t ws_size,
                              hipStream_t stream) {
    const int S = 2048, H = 2048;
    const long long MH = 16777216;         // 8192*2048 elements
    const long long HH = 4194304;          // 2048*2048
    const long long SH = (long long)S * H; // per-batch stride
    const long long SS = (long long)S * S;

    const float* X  = (const float*)d_in[0];
    const float* WQ = (const float*)d_in[1];
    const float* WK = (const float*)d_in[2];
    const float* WV = (const float*)d_in[3];
    float* out = (float*)d_out;

    unsigned short* Xb    = (unsigned short*)d_ws;
    unsigned short* WtAll = Xb + MH;        // [6144][2048]
    unsigned short* Qb    = WtAll + 3 * HH;
    unsigned short* Kb    = Qb + MH;
    unsigned short* Vt    = Kb + MH;        // [2048][8192]
    unsigned short* att   = Vt + MH;        // [4][2048][2048]

    cvt_f32_bf16<<<16384, 256, 0, stream>>>(X, Xb);
    cvt_transpose3<<<dim3(32, 32, 3), 256, 0, stream>>>(WQ, WK, WV, WtAll);

    // stage 1: merged QKV projection, N = 6144
    gemm_bt<1><<<dim3(48, 64), 256, 0, stream>>>(Xb, WtAll, nullptr, Qb, Kb, Vt,
                                                 H, H, H, 0, 0, 0);
    // stage 2: att = (Q K^T) * decay
    gemm_bt<3><<<dim3(16, 16, 4), 256, 0, stream>>>(Qb, Kb, att, nullptr, nullptr, nullptr,
                                                    H, H, H, SH, SH, SS);
    // stage 3: out^T = Vt x att (sA = 2048 = batch column offset into Vt[h][8192])
    gemm_bt<4><<<dim3(16, 16, 4), 256, 0, stream>>>(Vt, att, out, nullptr, nullptr, nullptr,
                                                    8192, S, S, S, SS, SH);
}